// Round 1
// baseline (698.955 us; speedup 1.0000x reference)
//
#include <hip/hip_runtime.h>

#define NUM_TASKS 8
#define NUM_TABLES 16
#define HASH 1000000
#define BATCH 8192
#define NNZ (BATCH * 20)
#define OFF_ROW (BATCH + 1)

// One thread per (table, bag). Accumulate all 8 task sums in registers.
__global__ void emb_pool_kernel(const float* __restrict__ W,      // [8][16][HASH]
                                const int* __restrict__ offsets,  // [16][8193]
                                const int* __restrict__ indices,  // [16][NNZ]
                                float* __restrict__ out)          // [8][8192][16]
{
    int gid = blockIdx.x * blockDim.x + threadIdx.x;
    if (gid >= NUM_TABLES * BATCH) return;
    int t = gid >> 13;        // table (8192 = 2^13 bags per table)
    int b = gid & (BATCH - 1);

    int start = offsets[t * OFF_ROW + b];
    int end   = offsets[t * OFF_ROW + b + 1];

    const int*   idxp = indices + (size_t)t * NNZ;
    const float* Wt   = W + (size_t)t * HASH;   // + task * (NUM_TABLES*HASH)

    float acc[NUM_TASKS];
#pragma unroll
    for (int k = 0; k < NUM_TASKS; ++k) acc[k] = 0.0f;

    for (int i = start; i < end; ++i) {
        int h = idxp[i];
#pragma unroll
        for (int task = 0; task < NUM_TASKS; ++task) {
            acc[task] += Wt[(size_t)task * (NUM_TABLES * (size_t)HASH) + h];
        }
    }

#pragma unroll
    for (int task = 0; task < NUM_TASKS; ++task) {
        out[(size_t)task * (BATCH * NUM_TABLES) + (size_t)b * NUM_TABLES + t] = acc[task];
    }
}

extern "C" void kernel_launch(void* const* d_in, const int* in_sizes, int n_in,
                              void* d_out, int out_size, void* d_ws, size_t ws_size,
                              hipStream_t stream) {
    const float* W       = (const float*)d_in[0];
    const int*   offsets = (const int*)d_in[1];
    const int*   indices = (const int*)d_in[2];
    float*       out     = (float*)d_out;

    const int total = NUM_TABLES * BATCH;   // 131072 threads
    const int block = 256;
    const int grid  = (total + block - 1) / block;
    emb_pool_kernel<<<grid, block, 0, stream>>>(W, offsets, indices, out);
}

// Round 2
// 416.276 us; speedup vs baseline: 1.6791x; 1.6791x over previous
//
#include <hip/hip_runtime.h>

#define NUM_TASKS 8
#define NUM_TABLES 16
#define HASH 1000000
#define BATCH 8192
#define NNZ (BATCH * 20)
#define OFF_ROW (BATCH + 1)

// One thread per (task, table, bag). task in low 3 bits of gid so each
// 8-lane group shares one bag's offsets/indices (broadcast loads), and the
// 8 gathers per index are spread across lanes instead of serialized in one
// thread. 1,048,576 threads -> 4096 blocks -> full occupancy at VGPR~16.
__global__ void emb_pool_kernel(const float* __restrict__ W,      // [8][16][HASH]
                                const int* __restrict__ offsets,  // [16][8193]
                                const int* __restrict__ indices,  // [16][NNZ]
                                float* __restrict__ out)          // [8][8192][16]
{
    int gid = blockIdx.x * blockDim.x + threadIdx.x;
    int task = gid & 7;
    int b    = (gid >> 3) & (BATCH - 1);
    int t    = gid >> 16;            // 16 tables, high bits -> tables stream in order

    int start = offsets[t * OFF_ROW + b];
    int end   = offsets[t * OFF_ROW + b + 1];

    const int*   idxp   = indices + (size_t)t * NNZ;
    const float* Wslice = W + ((size_t)task * NUM_TABLES + t) * (size_t)HASH;

    float acc = 0.0f;
    int i = start;
    // 4x unroll: 4 independent idx loads, then 4 independent gathers in flight.
    for (; i + 3 < end; i += 4) {
        int h0 = idxp[i];
        int h1 = idxp[i + 1];
        int h2 = idxp[i + 2];
        int h3 = idxp[i + 3];
        float w0 = Wslice[h0];
        float w1 = Wslice[h1];
        float w2 = Wslice[h2];
        float w3 = Wslice[h3];
        acc += w0; acc += w1; acc += w2; acc += w3;
    }
    for (; i < end; ++i) acc += Wslice[idxp[i]];

    out[((size_t)task * BATCH + b) * NUM_TABLES + t] = acc;
}

extern "C" void kernel_launch(void* const* d_in, const int* in_sizes, int n_in,
                              void* d_out, int out_size, void* d_ws, size_t ws_size,
                              hipStream_t stream) {
    const float* W       = (const float*)d_in[0];
    const int*   offsets = (const int*)d_in[1];
    const int*   indices = (const int*)d_in[2];
    float*       out     = (float*)d_out;

    const int total = NUM_TASKS * NUM_TABLES * BATCH;  // 1,048,576
    const int block = 256;
    const int grid  = total / block;                   // 4096
    emb_pool_kernel<<<grid, block, 0, stream>>>(W, offsets, indices, out);
}

// Round 3
// 373.336 us; speedup vs baseline: 1.8722x; 1.1150x over previous
//
#include <hip/hip_runtime.h>

#define NUM_TASKS 8
#define NUM_TABLES 16
#define HASH 1000000
#define BATCH 8192
#define NNZ (BATCH * 20)
#define OFF_ROW (BATCH + 1)

// One WAVE per (table, bag): lane = split*8 + task.
// - 8 "split" groups stride the segment (i = start+split, step 8)
// - 8 tasks gather from their own 64MB weight slice
// - cross-split reduction via shfl_xor(8,16,32)
// 2048 blocks per table == ~whole-GPU residency, so only ~1-2 tables'
// weight lines (30-60 MB) are concurrently live -> L3 captures the ~2.8x
// intra-slice line reuse that round 2 lost (FETCH was at zero-reuse bound).
__global__ void emb_pool_kernel(const float* __restrict__ W,      // [8][16][HASH]
                                const int* __restrict__ offsets,  // [16][8193]
                                const int* __restrict__ indices,  // [16][NNZ]
                                float* __restrict__ out)          // [8][8192][16]
{
    const int block = blockIdx.x;
    const int t        = block >> 11;              // 2048 blocks per table
    const int bag_base = (block & 2047) << 2;      // 4 bags per block (4 waves)
    const int wave     = threadIdx.x >> 6;
    const int b        = bag_base + wave;
    const int lane     = threadIdx.x & 63;
    const int task     = lane & 7;
    const int split    = lane >> 3;

    const int start = offsets[t * OFF_ROW + b];
    const int end   = offsets[t * OFF_ROW + b + 1];

    const int*   idxp   = indices + (size_t)t * NNZ;
    const float* Wslice = W + ((size_t)task * NUM_TABLES + t) * (size_t)HASH;

    float acc = 0.0f;
    for (int i = start + split; i < end; i += 8) {
        acc += Wslice[idxp[i]];
    }

    // reduce over the split dimension (lane bits 3,4,5)
    acc += __shfl_xor(acc, 8);
    acc += __shfl_xor(acc, 16);
    acc += __shfl_xor(acc, 32);

    if (split == 0) {
        out[((size_t)task * BATCH + b) * NUM_TABLES + t] = acc;
    }
}

extern "C" void kernel_launch(void* const* d_in, const int* in_sizes, int n_in,
                              void* d_out, int out_size, void* d_ws, size_t ws_size,
                              hipStream_t stream) {
    const float* W       = (const float*)d_in[0];
    const int*   offsets = (const int*)d_in[1];
    const int*   indices = (const int*)d_in[2];
    float*       out     = (float*)d_out;

    const int grid  = NUM_TABLES * 2048;   // 32768 blocks, 4 bags (waves) each
    const int block = 256;
    emb_pool_kernel<<<grid, block, 0, stream>>>(W, offsets, indices, out);
}